// Round 2
// baseline (474.510 us; speedup 1.0000x reference)
//
#include <hip/hip_runtime.h>
#include <hip/hip_bf16.h>

static constexpr int Lc     = 2048;
static constexpr int DIMc   = 512;
static constexpr int HEADSc = 8;
static constexpr int DHEADc = 64;
static constexpr int KSc    = 127;
static constexpr int FFc    = 2048;
static constexpr int NQKVc  = 1536;

// ---------------- LayerNorm: one 256-thread block per row (DIM=512) ----------
__global__ __launch_bounds__(256) void ln_kernel(const float* __restrict__ in,
                                                 const float* __restrict__ g,
                                                 const float* __restrict__ b,
                                                 float* __restrict__ out) {
  const int row = blockIdx.x;
  const int tid = threadIdx.x;
  const float* rp = in + (size_t)row * DIMc;
  float v0 = rp[tid];
  float v1 = rp[tid + 256];
  float s = v0 + v1;
  float sq = v0 * v0 + v1 * v1;
  __shared__ float rs[4], rq[4], stat[2];
#pragma unroll
  for (int o = 32; o > 0; o >>= 1) {
    s += __shfl_down(s, o);
    sq += __shfl_down(sq, o);
  }
  const int wid = tid >> 6, lane = tid & 63;
  if (lane == 0) { rs[wid] = s; rq[wid] = sq; }
  __syncthreads();
  if (tid == 0) {
    float S = rs[0] + rs[1] + rs[2] + rs[3];
    float Q = rq[0] + rq[1] + rq[2] + rq[3];
    float m = S / DIMc;
    float var = Q / DIMc - m * m;
    stat[0] = m;
    stat[1] = rsqrtf(var + 1e-5f);
  }
  __syncthreads();
  const float m = stat[0], r = stat[1];
  out[(size_t)row * DIMc + tid] = (v0 - m) * r * g[tid] + b[tid];
  out[(size_t)row * DIMc + tid + 256] =
      (v1 - m) * r * g[tid + 256] + b[tid + 256];
}

// ---------------- GEMM: C[M,N] = A[M,K] @ W[K,N] + bias ---------------------
// OP: 0 = none, 1 = exact GELU, 2 = add residual
template <int OP>
__global__ __launch_bounds__(256) void gemm_kernel(
    const float* __restrict__ A, const float* __restrict__ W,
    const float* __restrict__ bias, const float* __restrict__ res,
    float* __restrict__ C, int M, int N, int K) {
  constexpr int BM = 64, BN = 64, BK = 16;
  __shared__ float As[BK][BM + 1];
  __shared__ float Ws[BK][BN + 1];
  const int tid = threadIdx.x;
  const int bx = blockIdx.x, by = blockIdx.y;
  const int tx = tid & 15, ty = tid >> 4;
  const int ty4 = ty * 4, tx4 = tx * 4;
  const int row0 = by * BM + ty4;
  const int col0 = bx * BN + tx4;

  // A-tile load indices: one float4 per thread (64 rows x 16 k)
  const int ar = tid >> 2;        // 0..63
  const int ak = (tid & 3) * 4;   // 0,4,8,12
  // W-tile load indices: one float4 per thread (16 k x 64 cols)
  const int wr = tid >> 4;        // 0..15
  const int wc = (tid & 15) * 4;  // col within tile

  float acc[4][4] = {};

  for (int k0 = 0; k0 < K; k0 += BK) {
    const float4 av =
        *(const float4*)(A + (size_t)(by * BM + ar) * K + k0 + ak);
    As[ak + 0][ar] = av.x;
    As[ak + 1][ar] = av.y;
    As[ak + 2][ar] = av.z;
    As[ak + 3][ar] = av.w;
    const float4 wv =
        *(const float4*)(W + (size_t)(k0 + wr) * N + bx * BN + wc);
    Ws[wr][wc + 0] = wv.x;
    Ws[wr][wc + 1] = wv.y;
    Ws[wr][wc + 2] = wv.z;
    Ws[wr][wc + 3] = wv.w;
    __syncthreads();
#pragma unroll
    for (int kk = 0; kk < BK; ++kk) {
      float a0 = As[kk][ty4 + 0], a1 = As[kk][ty4 + 1];
      float a2 = As[kk][ty4 + 2], a3 = As[kk][ty4 + 3];
      float w0 = Ws[kk][tx4 + 0], w1 = Ws[kk][tx4 + 1];
      float w2 = Ws[kk][tx4 + 2], w3 = Ws[kk][tx4 + 3];
      acc[0][0] += a0 * w0; acc[0][1] += a0 * w1;
      acc[0][2] += a0 * w2; acc[0][3] += a0 * w3;
      acc[1][0] += a1 * w0; acc[1][1] += a1 * w1;
      acc[1][2] += a1 * w2; acc[1][3] += a1 * w3;
      acc[2][0] += a2 * w0; acc[2][1] += a2 * w1;
      acc[2][2] += a2 * w2; acc[2][3] += a2 * w3;
      acc[3][0] += a3 * w0; acc[3][1] += a3 * w1;
      acc[3][2] += a3 * w2; acc[3][3] += a3 * w3;
    }
    __syncthreads();
  }

#pragma unroll
  for (int i = 0; i < 4; ++i) {
    const int r = row0 + i;
#pragma unroll
    for (int j = 0; j < 4; ++j) {
      const int c = col0 + j;
      float v = acc[i][j] + bias[c];
      if (OP == 1) v = 0.5f * v * (1.0f + erff(v * 0.70710678118f));
      const size_t o = (size_t)r * N + c;
      if (OP == 2) v += res[o];
      C[o] = v;
    }
  }
}

// ---------------- Neighborhood attention: one 128-thread block per (l,h) ----
__global__ __launch_bounds__(128) void attn_kernel(
    const float* __restrict__ qkv, const float* __restrict__ rpb,
    float* __restrict__ out) {
  const int l = blockIdx.x, h = blockIdx.y, tid = threadIdx.x;
  int start = l - (KSc / 2);
  if (start < 0) start = 0;
  if (start > Lc - KSc) start = Lc - KSc;

  __shared__ float qs[DHEADc];
  __shared__ float ps[128];
  __shared__ float sm[128];

  const float scale = 0.125f;  // 64^-0.5
  if (tid < DHEADc) qs[tid] = qkv[(size_t)l * NQKVc + h * DHEADc + tid] * scale;
  __syncthreads();

  float logit = -1e30f;
  if (tid < KSc) {
    const float* kp = qkv + (size_t)(start + tid) * NQKVc + DIMc + h * DHEADc;
    float acc = 0.f;
#pragma unroll
    for (int d = 0; d < DHEADc; ++d) acc += qs[d] * kp[d];
    logit = acc + rpb[h * (2 * KSc - 1) + start + tid - l + KSc - 1];
  }

  sm[tid] = logit;
  __syncthreads();
#pragma unroll
  for (int s = 64; s > 0; s >>= 1) {
    if (tid < s) sm[tid] = fmaxf(sm[tid], sm[tid + s]);
    __syncthreads();
  }
  const float m = sm[0];
  __syncthreads();

  const float p = (tid < KSc) ? __expf(logit - m) : 0.f;
  ps[tid] = p;
  sm[tid] = p;
  __syncthreads();
#pragma unroll
  for (int s = 64; s > 0; s >>= 1) {
    if (tid < s) sm[tid] += sm[tid + s];
    __syncthreads();
  }
  const float inv = 1.f / sm[0];

  if (tid < DHEADc) {
    float o = 0.f;
    const float* vp =
        qkv + (size_t)start * NQKVc + 2 * DIMc + h * DHEADc + tid;
    for (int kk = 0; kk < KSc; ++kk) o += ps[kk] * vp[(size_t)kk * NQKVc];
    out[(size_t)l * DIMc + h * DHEADc + tid] = o * inv;
  }
}

// ---------------------------------------------------------------------------
extern "C" void kernel_launch(void* const* d_in, const int* in_sizes, int n_in,
                              void* d_out, int out_size, void* d_ws,
                              size_t ws_size, hipStream_t stream) {
  const float* x      = (const float*)d_in[0];
  const float* ln1_g  = (const float*)d_in[1];
  const float* ln1_b  = (const float*)d_in[2];
  const float* qkv_w  = (const float*)d_in[3];
  const float* qkv_b  = (const float*)d_in[4];
  const float* rpb    = (const float*)d_in[5];
  const float* proj_w = (const float*)d_in[6];
  const float* proj_b = (const float*)d_in[7];
  const float* ln2_g  = (const float*)d_in[8];
  const float* ln2_b  = (const float*)d_in[9];
  const float* ff1_w  = (const float*)d_in[10];
  const float* ff1_b  = (const float*)d_in[11];
  const float* ff2_w  = (const float*)d_in[12];
  const float* ff2_b  = (const float*)d_in[13];
  float* out = (float*)d_out;

  char* ws = (char*)d_ws;
  float* lnbuf = (float*)(ws);                        // 4 MB (ln1, then ln2)
  float* qkv   = (float*)(ws + ((size_t)4 << 20));    // 12 MB
  float* attn  = (float*)(ws + ((size_t)16 << 20));   // 4 MB
  float* x2    = (float*)(ws + ((size_t)20 << 20));   // 4 MB
  float* ff1   = (float*)(ws + ((size_t)24 << 20));   // 16 MB

  // 1) LN1
  ln_kernel<<<Lc, 256, 0, stream>>>(x, ln1_g, ln1_b, lnbuf);
  // 2) QKV GEMM
  gemm_kernel<0><<<dim3(NQKVc / 64, Lc / 64), 256, 0, stream>>>(
      lnbuf, qkv_w, qkv_b, nullptr, qkv, Lc, NQKVc, DIMc);
  // 3) Neighborhood attention
  attn_kernel<<<dim3(Lc, HEADSc), 128, 0, stream>>>(qkv, rpb, attn);
  // 4) proj GEMM + residual(x) -> x2
  gemm_kernel<2><<<dim3(DIMc / 64, Lc / 64), 256, 0, stream>>>(
      attn, proj_w, proj_b, x, x2, Lc, DIMc, DIMc);
  // 5) LN2
  ln_kernel<<<Lc, 256, 0, stream>>>(x2, ln2_g, ln2_b, lnbuf);
  // 6) FF1 GEMM + exact GELU
  gemm_kernel<1><<<dim3(FFc / 64, Lc / 64), 256, 0, stream>>>(
      lnbuf, ff1_w, ff1_b, nullptr, ff1, Lc, FFc, DIMc);
  // 7) FF2 GEMM + residual(x2) -> out
  gemm_kernel<2><<<dim3(DIMc / 64, Lc / 64), 256, 0, stream>>>(
      ff1, ff2_w, ff2_b, x2, out, Lc, DIMc, FFc);
}

// Round 3
// 170.462 us; speedup vs baseline: 2.7837x; 2.7837x over previous
//
#include <hip/hip_runtime.h>
#include <hip/hip_bf16.h>

static constexpr int Lc     = 2048;
static constexpr int DIMc   = 512;
static constexpr int HEADSc = 8;
static constexpr int DHEADc = 64;
static constexpr int KSc    = 127;
static constexpr int NQKVc  = 1536;

typedef __attribute__((ext_vector_type(8))) short short8;
typedef __attribute__((ext_vector_type(4))) float f32x4;
typedef unsigned short u16;

__device__ __forceinline__ float b2f(u16 s) {
  return __uint_as_float(((unsigned)s) << 16);
}
__device__ __forceinline__ u16 f2b(float x) {  // RNE
  unsigned u = __float_as_uint(x);
  return (u16)((u + 0x7fffu + ((u >> 16) & 1u)) >> 16);
}
__device__ __forceinline__ void gload16(const void* g, void* l) {
  __builtin_amdgcn_global_load_lds(
      (const __attribute__((address_space(1))) unsigned int*)g,
      (__attribute__((address_space(3))) unsigned int*)l, 16, 0, 0);
}

// ---------------- weight transpose + f32->bf16:  W[K][N] -> Wt[N][K] --------
__global__ __launch_bounds__(256) void wtrans_kernel(const float* __restrict__ W,
                                                     u16* __restrict__ Wt,
                                                     int K, int N) {
  __shared__ float t[32][33];
  const int bx = blockIdx.x, by = blockIdx.y;  // bx over N/32, by over K/32
  const int c = threadIdx.x & 31, r0 = threadIdx.x >> 5;
#pragma unroll
  for (int i = 0; i < 4; ++i) {
    const int r = r0 + i * 8;
    t[r][c] = W[(size_t)(by * 32 + r) * N + bx * 32 + c];
  }
  __syncthreads();
#pragma unroll
  for (int i = 0; i < 4; ++i) {
    const int r = r0 + i * 8;
    Wt[(size_t)(bx * 32 + r) * K + by * 32 + c] = f2b(t[c][r]);
  }
}

// ---------------- LayerNorm: f32 in -> bf16 out ----------------------------
__global__ __launch_bounds__(256) void ln_kernel(const float* __restrict__ in,
                                                 const float* __restrict__ g,
                                                 const float* __restrict__ b,
                                                 u16* __restrict__ out) {
  const int row = blockIdx.x;
  const int tid = threadIdx.x;
  const float* rp = in + (size_t)row * DIMc;
  float v0 = rp[tid];
  float v1 = rp[tid + 256];
  float s = v0 + v1;
  float sq = v0 * v0 + v1 * v1;
  __shared__ float rs[4], rq[4], stat[2];
#pragma unroll
  for (int o = 32; o > 0; o >>= 1) {
    s += __shfl_down(s, o);
    sq += __shfl_down(sq, o);
  }
  const int wid = tid >> 6, lane = tid & 63;
  if (lane == 0) { rs[wid] = s; rq[wid] = sq; }
  __syncthreads();
  if (tid == 0) {
    float S = rs[0] + rs[1] + rs[2] + rs[3];
    float Q = rq[0] + rq[1] + rq[2] + rq[3];
    float m = S / DIMc;
    float var = Q / DIMc - m * m;
    stat[0] = m;
    stat[1] = rsqrtf(var + 1e-5f);
  }
  __syncthreads();
  const float m = stat[0], r = stat[1];
  out[(size_t)row * DIMc + tid] = f2b((v0 - m) * r * g[tid] + b[tid]);
  out[(size_t)row * DIMc + tid + 256] =
      f2b((v1 - m) * r * g[tid + 256] + b[tid + 256]);
}

// ---------------- MFMA GEMM: C[M,N] = A[M,K](bf16) @ Bt[N,K](bf16)^T -------
// OP: 0 = bias only (bf16 out), 1 = bias+GELU (bf16 out), 2 = bias+res (f32 out)
template <int OP, typename OUT_T>
__global__ __launch_bounds__(256) void mfma_gemm(
    const u16* __restrict__ A, const u16* __restrict__ Bt,
    const float* __restrict__ bias, const float* __restrict__ res,
    OUT_T* __restrict__ C, int M, int N, int K) {
  constexpr int BM = 128, BN = 128, BK = 32;
  __shared__ __align__(16) u16 As[BM * BK];
  __shared__ __align__(16) u16 Bs[BN * BK];
  const int tid = threadIdx.x;
  const int wave = tid >> 6, lane = tid & 63;
  const int m0 = blockIdx.y * BM, n0 = blockIdx.x * BN;
  const int wm = (wave >> 1) * 64, wn = (wave & 1) * 64;

  f32x4 acc[4][4] = {};

  const int fr = lane & 15;
  const int fk8 = (lane >> 4) * 8;

  for (int k0 = 0; k0 < K; k0 += BK) {
#pragma unroll
    for (int i = 0; i < 2; ++i) {
      const int lin = i * 4096 + tid * 16;           // byte offset in tile
      const int row = lin >> 6, colb = lin & 63;     // 64B per row
      const int ldsbase = (i * 4096 + wave * 1024) >> 1;  // elem index
      gload16(A + (size_t)(m0 + row) * K + k0 + (colb >> 1), &As[ldsbase]);
      gload16(Bt + (size_t)(n0 + row) * K + k0 + (colb >> 1), &Bs[ldsbase]);
    }
    __syncthreads();

    short8 af[4], bfr[4];
#pragma unroll
    for (int i = 0; i < 4; ++i)
      af[i] = *(const short8*)&As[(wm + i * 16 + fr) * BK + fk8];
#pragma unroll
    for (int j = 0; j < 4; ++j)
      bfr[j] = *(const short8*)&Bs[(wn + j * 16 + fr) * BK + fk8];
#pragma unroll
    for (int i = 0; i < 4; ++i)
#pragma unroll
      for (int j = 0; j < 4; ++j)
        acc[i][j] =
            __builtin_amdgcn_mfma_f32_16x16x32_bf16(af[i], bfr[j], acc[i][j], 0, 0, 0);
    __syncthreads();
  }

  // epilogue: C/D layout col = lane&15, row = (lane>>4)*4 + reg
  const int cl = lane & 15;
  const int rbase = (lane >> 4) * 4;
#pragma unroll
  for (int i = 0; i < 4; ++i) {
#pragma unroll
    for (int j = 0; j < 4; ++j) {
      const int c = n0 + wn + j * 16 + cl;
      const float bv = bias[c];
#pragma unroll
      for (int r = 0; r < 4; ++r) {
        const int row = m0 + wm + i * 16 + rbase + r;
        float v = acc[i][j][r] + bv;
        if (OP == 1) v = 0.5f * v * (1.0f + erff(v * 0.70710678118f));
        const size_t o = (size_t)row * N + c;
        if (OP == 2) {
          ((float*)C)[o] = v + res[o];
        } else {
          ((u16*)C)[o] = f2b(v);
        }
      }
    }
  }
}

// ---------------- Neighborhood attention, tile of 32 queries x 1 head ------
__global__ __launch_bounds__(256) void attn_kernel(
    const u16* __restrict__ qkv, const float* __restrict__ rpb,
    u16* __restrict__ out) {
  constexpr int LT = 32, NR = 158, KP = 72, QP = 68;
  const int h = blockIdx.y, lt = blockIdx.x, tid = threadIdx.x;
  const int l0 = lt * LT;

  int s_min = l0 - 63;
  if (s_min < 0) s_min = 0;
  if (s_min > Lc - KSc) s_min = Lc - KSc;

  __shared__ __align__(16) float Qs[LT][QP];
  __shared__ __align__(16) u16 Ks[NR][KP];
  __shared__ __align__(16) u16 Vs[NR][KP];
  __shared__ __align__(16) u16 Ps[LT][128];
  __shared__ float rp[2 * KSc - 1];

  for (int i = tid; i < LT * DHEADc; i += 256) {
    const int l = i >> 6, d = i & 63;
    Qs[l][d] = b2f(qkv[(size_t)(l0 + l) * NQKVc + h * DHEADc + d]) * 0.125f;
  }
  for (int i = tid; i < 2 * KSc - 1; i += 256) rp[i] = rpb[h * (2 * KSc - 1) + i];
  for (int i = tid; i < NR * 8; i += 256) {
    const int r = i >> 3, seg = i & 7;
    const int gr = s_min + r;
    if (gr < Lc) {
      const size_t gb = (size_t)gr * NQKVc + h * DHEADc + seg * 8;
      *(short8*)&Ks[r][seg * 8] = *(const short8*)(qkv + gb + DIMc);
      *(short8*)&Vs[r][seg * 8] = *(const short8*)(qkv + gb + 2 * DIMc);
    }
  }
  __syncthreads();

  const int lq = tid >> 3, c = tid & 7;
  const int l = l0 + lq;
  int st = l - 63;
  if (st < 0) st = 0;
  if (st > Lc - KSc) st = Lc - KSc;
  const int off = st - s_min;
  const int bias0 = st - l + 126;

  float lg[16];
#pragma unroll
  for (int p = 0; p < 16; ++p) {
    const int k = c + p * 8;
    float a = -1e30f;
    if (k < KSc) {
      a = 0.f;
#pragma unroll
      for (int d8 = 0; d8 < 8; ++d8) {
        const short8 kv = *(const short8*)&Ks[off + k][d8 * 8];
        const float4 q0 = *(const float4*)&Qs[lq][d8 * 8];
        const float4 q1 = *(const float4*)&Qs[lq][d8 * 8 + 4];
        a += q0.x * b2f((u16)kv[0]) + q0.y * b2f((u16)kv[1]) +
             q0.z * b2f((u16)kv[2]) + q0.w * b2f((u16)kv[3]) +
             q1.x * b2f((u16)kv[4]) + q1.y * b2f((u16)kv[5]) +
             q1.z * b2f((u16)kv[6]) + q1.w * b2f((u16)kv[7]);
      }
      a += rp[bias0 + k];
    }
    lg[p] = a;
  }

  float mx = -1e30f;
#pragma unroll
  for (int p = 0; p < 16; ++p) mx = fmaxf(mx, lg[p]);
#pragma unroll
  for (int o = 1; o < 8; o <<= 1) mx = fmaxf(mx, __shfl_xor(mx, o));
  float sm = 0.f;
#pragma unroll
  for (int p = 0; p < 16; ++p) {
    lg[p] = __expf(lg[p] - mx);
    sm += lg[p];
  }
#pragma unroll
  for (int o = 1; o < 8; o <<= 1) sm += __shfl_xor(sm, o);
  const float inv = 1.f / sm;
#pragma unroll
  for (int p = 0; p < 16; ++p) Ps[lq][c + p * 8] = f2b(lg[p] * inv);
  __syncthreads();

  // PV: thread handles (lq, d = c*8 .. c*8+7)
  float o8[8] = {};
  for (int k = 0; k < KSc; ++k) {
    const float p = b2f(Ps[lq][k]);
    const short8 vv = *(const short8*)&Vs[off + k][c * 8];
    o8[0] += p * b2f((u16)vv[0]);
    o8[1] += p * b2f((u16)vv[1]);
    o8[2] += p * b2f((u16)vv[2]);
    o8[3] += p * b2f((u16)vv[3]);
    o8[4] += p * b2f((u16)vv[4]);
    o8[5] += p * b2f((u16)vv[5]);
    o8[6] += p * b2f((u16)vv[6]);
    o8[7] += p * b2f((u16)vv[7]);
  }
  short8 ov;
#pragma unroll
  for (int q = 0; q < 8; ++q) ov[q] = (short)f2b(o8[q]);
  *(short8*)(out + (size_t)(l0 + lq) * DIMc + h * DHEADc + c * 8) = ov;
}

// ---------------------------------------------------------------------------
extern "C" void kernel_launch(void* const* d_in, const int* in_sizes, int n_in,
                              void* d_out, int out_size, void* d_ws,
                              size_t ws_size, hipStream_t stream) {
  const float* x      = (const float*)d_in[0];
  const float* ln1_g  = (const float*)d_in[1];
  const float* ln1_b  = (const float*)d_in[2];
  const float* qkv_w  = (const float*)d_in[3];
  const float* qkv_b  = (const float*)d_in[4];
  const float* rpb    = (const float*)d_in[5];
  const float* proj_w = (const float*)d_in[6];
  const float* proj_b = (const float*)d_in[7];
  const float* ln2_g  = (const float*)d_in[8];
  const float* ln2_b  = (const float*)d_in[9];
  const float* ff1_w  = (const float*)d_in[10];
  const float* ff1_b  = (const float*)d_in[11];
  const float* ff2_w  = (const float*)d_in[12];
  const float* ff2_b  = (const float*)d_in[13];
  float* out = (float*)d_out;

  char* ws = (char*)d_ws;
  u16*   lnbuf   = (u16*)(ws);                         // 2 MB
  u16*   qkvbuf  = (u16*)(ws + ((size_t)2  << 20));    // 6 MB
  u16*   attnbuf = (u16*)(ws + ((size_t)8  << 20));    // 2 MB
  float* x2      = (float*)(ws + ((size_t)10 << 20));  // 4 MB
  u16*   ff1buf  = (u16*)(ws + ((size_t)14 << 20));    // 8 MB
  u16*   wt_qkv  = (u16*)(ws + ((size_t)22 << 20));    // 1.5 MB
  u16*   wt_proj = (u16*)(ws + ((size_t)24 << 20));    // 0.5 MB
  u16*   wt_ff1  = (u16*)(ws + ((size_t)25 << 20));    // 2 MB
  u16*   wt_ff2  = (u16*)(ws + ((size_t)27 << 20));    // 2 MB

  // weight transposes (f32 [K][N] -> bf16 [N][K])
  wtrans_kernel<<<dim3(NQKVc / 32, DIMc / 32), 256, 0, stream>>>(qkv_w, wt_qkv, DIMc, NQKVc);
  wtrans_kernel<<<dim3(DIMc / 32, DIMc / 32), 256, 0, stream>>>(proj_w, wt_proj, DIMc, DIMc);
  wtrans_kernel<<<dim3(4 * DIMc / 32, DIMc / 32), 256, 0, stream>>>(ff1_w, wt_ff1, DIMc, 4 * DIMc);
  wtrans_kernel<<<dim3(DIMc / 32, 4 * DIMc / 32), 256, 0, stream>>>(ff2_w, wt_ff2, 4 * DIMc, DIMc);

  // 1) LN1
  ln_kernel<<<Lc, 256, 0, stream>>>(x, ln1_g, ln1_b, lnbuf);
  // 2) QKV GEMM (bf16 out)
  mfma_gemm<0, u16><<<dim3(NQKVc / 128, Lc / 128), 256, 0, stream>>>(
      lnbuf, wt_qkv, qkv_b, nullptr, qkvbuf, Lc, NQKVc, DIMc);
  // 3) attention
  attn_kernel<<<dim3(Lc / 32, HEADSc), 256, 0, stream>>>(qkvbuf, rpb, attnbuf);
  // 4) proj GEMM + residual(x) -> x2 (f32)
  mfma_gemm<2, float><<<dim3(DIMc / 128, Lc / 128), 256, 0, stream>>>(
      attnbuf, wt_proj, proj_b, x, x2, Lc, DIMc, DIMc);
  // 5) LN2
  ln_kernel<<<Lc, 256, 0, stream>>>(x2, ln2_g, ln2_b, lnbuf);
  // 6) FF1 GEMM + GELU (bf16 out)
  mfma_gemm<1, u16><<<dim3(4 * DIMc / 128, Lc / 128), 256, 0, stream>>>(
      lnbuf, wt_ff1, ff1_b, nullptr, ff1buf, Lc, 4 * DIMc, DIMc);
  // 7) FF2 GEMM + residual(x2) -> out (f32)
  mfma_gemm<2, float><<<dim3(DIMc / 128, Lc / 128), 256, 0, stream>>>(
      ff1buf, wt_ff2, ff2_b, x2, out, Lc, DIMc, 4 * DIMc);
}

// Round 4
// 95.638 us; speedup vs baseline: 4.9615x; 1.7824x over previous
//
#include <hip/hip_runtime.h>
#include <hip/hip_bf16.h>

static constexpr int Lc     = 2048;
static constexpr int DIMc   = 512;
static constexpr int HEADSc = 8;
static constexpr int DHEADc = 64;
static constexpr int KSc    = 127;
static constexpr int NQKVc  = 1536;

typedef __attribute__((ext_vector_type(8))) short short8;
typedef __attribute__((ext_vector_type(4))) float f32x4;
typedef unsigned short u16;
typedef unsigned int u32;

__device__ __forceinline__ float b2f(u16 s) {
  return __uint_as_float(((u32)s) << 16);
}
__device__ __forceinline__ u16 f2b(float x) {  // RNE
  u32 u = __float_as_uint(x);
  return (u16)((u + 0x7fffu + ((u >> 16) & 1u)) >> 16);
}
__device__ __forceinline__ void gload16(const void* g, void* l) {
  __builtin_amdgcn_global_load_lds(
      (const __attribute__((address_space(1))) u32*)g,
      (__attribute__((address_space(3))) u32*)l, 16, 0, 0);
}

// ---------------- fused weight transpose + f32->bf16: W[K][N] -> Wt[N][K] ---
__global__ __launch_bounds__(256) void wtrans_all(
    const float* __restrict__ w0, const float* __restrict__ w1,
    const float* __restrict__ w2, const float* __restrict__ w3,
    u16* __restrict__ o0, u16* __restrict__ o1, u16* __restrict__ o2,
    u16* __restrict__ o3) {
  int t = blockIdx.x;
  const float* W;
  u16* O;
  int K, N;
  if (t < 768)       { W = w0; O = o0; K = 512;  N = 1536; }
  else if (t < 1024) { W = w1; O = o1; K = 512;  N = 512;  t -= 768; }
  else if (t < 2048) { W = w2; O = o2; K = 512;  N = 2048; t -= 1024; }
  else               { W = w3; O = o3; K = 2048; N = 512;  t -= 2048; }
  const int nt = N >> 5;
  const int by = t / nt, bx = t % nt;
  __shared__ float tl[32][33];
  const int c = threadIdx.x & 31, r0 = threadIdx.x >> 5;
#pragma unroll
  for (int i = 0; i < 4; ++i) {
    const int r = r0 + i * 8;
    tl[r][c] = W[(size_t)(by * 32 + r) * N + bx * 32 + c];
  }
  __syncthreads();
#pragma unroll
  for (int i = 0; i < 4; ++i) {
    const int r = r0 + i * 8;
    O[(size_t)(bx * 32 + r) * K + by * 32 + c] = f2b(tl[c][r]);
  }
}

// ---------------- LayerNorm: f32 in -> bf16 out ----------------------------
__global__ __launch_bounds__(256) void ln_kernel(const float* __restrict__ in,
                                                 const float* __restrict__ g,
                                                 const float* __restrict__ b,
                                                 u16* __restrict__ out) {
  const int row = blockIdx.x;
  const int tid = threadIdx.x;
  const float* rp = in + (size_t)row * DIMc;
  float v0 = rp[tid];
  float v1 = rp[tid + 256];
  float s = v0 + v1;
  float sq = v0 * v0 + v1 * v1;
  __shared__ float rs[4], rq[4], stat[2];
#pragma unroll
  for (int o = 32; o > 0; o >>= 1) {
    s += __shfl_down(s, o);
    sq += __shfl_down(sq, o);
  }
  const int wid = tid >> 6, lane = tid & 63;
  if (lane == 0) { rs[wid] = s; rq[wid] = sq; }
  __syncthreads();
  if (tid == 0) {
    float S = rs[0] + rs[1] + rs[2] + rs[3];
    float Q = rq[0] + rq[1] + rq[2] + rq[3];
    float m = S / DIMc;
    float var = Q / DIMc - m * m;
    stat[0] = m;
    stat[1] = rsqrtf(var + 1e-5f);
  }
  __syncthreads();
  const float m = stat[0], r = stat[1];
  out[(size_t)row * DIMc + tid] = f2b((v0 - m) * r * g[tid] + b[tid]);
  out[(size_t)row * DIMc + tid + 256] =
      f2b((v1 - m) * r * g[tid + 256] + b[tid + 256]);
}

// ---------------- MFMA GEMM: C[M,N] = A[M,K](bf16) @ Bt[N,K](bf16)^T -------
// OP: 0 bias (bf16 out), 1 bias+GELU (bf16 out), 2 bias+res (f32 out),
//     3 split-K partial (bf16, no bias)
template <int OP, int SPLIT, typename OUT_T>
__global__ __launch_bounds__(256) void mfma_gemm(
    const u16* __restrict__ A, const u16* __restrict__ Bt,
    const float* __restrict__ bias, const float* __restrict__ res,
    OUT_T* __restrict__ C, int M, int N, int K) {
  constexpr int BM = 128, BN = 128, BK = 32;
  __shared__ __align__(16) u16 As[BM * BK];
  __shared__ __align__(16) u16 Bs[BN * BK];
  const int tid = threadIdx.x;
  const int wave = tid >> 6, lane = tid & 63;
  const int m0 = blockIdx.y * BM, n0 = blockIdx.x * BN;
  const int wm = (wave >> 1) * 64, wn = (wave & 1) * 64;
  const int z = (SPLIT > 1) ? blockIdx.z : 0;
  const int kslice = K / SPLIT;
  const int kbeg = z * kslice;

  f32x4 acc[4][4] = {};

  const int fr = lane & 15;
  const int fk8 = (lane >> 4) * 8;

  for (int k0 = kbeg; k0 < kbeg + kslice; k0 += BK) {
#pragma unroll
    for (int i = 0; i < 2; ++i) {
      const int lin = i * 4096 + tid * 16;
      const int row = lin >> 6, colb = lin & 63;
      const int ldsbase = (i * 4096 + wave * 1024) >> 1;
      gload16(A + (size_t)(m0 + row) * K + k0 + (colb >> 1), &As[ldsbase]);
      gload16(Bt + (size_t)(n0 + row) * K + k0 + (colb >> 1), &Bs[ldsbase]);
    }
    __syncthreads();

    short8 af[4], bfr[4];
#pragma unroll
    for (int i = 0; i < 4; ++i)
      af[i] = *(const short8*)&As[(wm + i * 16 + fr) * BK + fk8];
#pragma unroll
    for (int j = 0; j < 4; ++j)
      bfr[j] = *(const short8*)&Bs[(wn + j * 16 + fr) * BK + fk8];
#pragma unroll
    for (int i = 0; i < 4; ++i)
#pragma unroll
      for (int j = 0; j < 4; ++j)
        acc[i][j] = __builtin_amdgcn_mfma_f32_16x16x32_bf16(af[i], bfr[j],
                                                            acc[i][j], 0, 0, 0);
    __syncthreads();
  }

  const int cl = lane & 15;
  const int rbase = (lane >> 4) * 4;
#pragma unroll
  for (int i = 0; i < 4; ++i) {
#pragma unroll
    for (int j = 0; j < 4; ++j) {
      const int c = n0 + wn + j * 16 + cl;
      const float bv = (OP == 3) ? 0.f : bias[c];
#pragma unroll
      for (int r = 0; r < 4; ++r) {
        const int row = m0 + wm + i * 16 + rbase + r;
        float v = acc[i][j][r] + bv;
        if (OP == 1) v = 0.5f * v * (1.0f + erff(v * 0.70710678118f));
        const size_t o = (size_t)row * N + c;
        if (OP == 2) {
          ((float*)C)[o] = v + res[o];
        } else if (OP == 3) {
          ((u16*)C)[(size_t)z * M * N + o] = f2b(v);
        } else {
          ((u16*)C)[o] = f2b(v);
        }
      }
    }
  }
}

// ---------------- split-K reduce for ff2: out = x2 + bias + sum(parts) -----
__global__ __launch_bounds__(256) void ff2_reduce(const u16* __restrict__ part,
                                                  const float* __restrict__ x2,
                                                  const float* __restrict__ bias,
                                                  float* __restrict__ out) {
  const int i = blockIdx.x * 256 + threadIdx.x;  // vec4 id
  const size_t b = (size_t)i * 4;
  const int col = (int)(b & (DIMc - 1));
  const float4 r = *(const float4*)(x2 + b);
  const float4 bb = *(const float4*)(bias + col);
  float4 s = {r.x + bb.x, r.y + bb.y, r.z + bb.z, r.w + bb.w};
#pragma unroll
  for (int zz = 0; zz < 4; ++zz) {
    const ushort4 p =
        *(const ushort4*)(part + (size_t)zz * (Lc * DIMc) + b);
    s.x += b2f(p.x);
    s.y += b2f(p.y);
    s.z += b2f(p.z);
    s.w += b2f(p.w);
  }
  *(float4*)(out + b) = s;
}

// ---------------- MFMA neighborhood attention: 64 queries x 1 head / block -
// 4 waves, one 16-query tile each. Key window union = 192 rows.
__global__ __launch_bounds__(256) void attn_mfma(const u16* __restrict__ qkv,
                                                 const float* __restrict__ rpb,
                                                 u16* __restrict__ out) {
  constexpr int NR = 192, NT = 12, PP = 200;
  __shared__ __align__(16) u16 Ks[NR * DHEADc];   // [r][d], seg ^ (r&7)
  __shared__ __align__(16) u16 Vt[DHEADc * NR];   // [d][r], seg ^ (d&7)
  __shared__ __align__(16) u16 Ps[4][16 * PP];    // per-wave P, stride 200
  __shared__ float rp[2 * KSc - 1];
  const int h = blockIdx.y, l0 = blockIdx.x * 64, tid = threadIdx.x;
  const int wv = tid >> 6, lane = tid & 63;
  const int fr = lane & 15, hi = lane >> 4;

  int s_min = l0 - 63;
  if (s_min < 0) s_min = 0;
  if (s_min > Lc - KSc) s_min = Lc - KSc;

  for (int i = tid; i < 2 * KSc - 1; i += 256) rp[i] = rpb[h * (2 * KSc - 1) + i];

  // ---- K stage: global_load_lds, pre-swizzled source, linear LDS ----------
#pragma unroll
  for (int rd = 0; rd < 6; ++rd) {
    const int linear = rd * 4096 + wv * 1024 + lane * 16;  // byte
    const int row = linear >> 7;          // 128B per row
    const int seg = (linear >> 4) & 7;
    const int segp = seg ^ (row & 7);
    int gl = s_min + row;
    if (gl > Lc - 1) gl = Lc - 1;
    gload16(qkv + (size_t)gl * NQKVc + DIMc + h * DHEADc + segp * 8,
            (char*)Ks + rd * 4096 + wv * 1024);
  }

  // ---- V stage: reg transpose -> Vt[d][r], swizzled b32 writes ------------
#pragma unroll
  for (int rd = 0; rd < 3; ++rd) {
    const int t = rd * 256 + tid;
    const int rpair = t >> 3, seg = t & 7;
    const int r0 = rpair * 2;
    int g0 = s_min + r0, g1 = s_min + r0 + 1;
    if (g0 > Lc - 1) g0 = Lc - 1;
    if (g1 > Lc - 1) g1 = Lc - 1;
    const short8 a =
        *(const short8*)(qkv + (size_t)g0 * NQKVc + 2 * DIMc + h * DHEADc + seg * 8);
    const short8 bq =
        *(const short8*)(qkv + (size_t)g1 * NQKVc + 2 * DIMc + h * DHEADc + seg * 8);
#pragma unroll
    for (int j = 0; j < 8; ++j) {
      const int d = seg * 8 + j;
      int byte = d * (NR * 2) + r0 * 2;
      byte ^= (d & 7) << 4;
      *(u32*)((char*)Vt + byte) =
          ((u32)(u16)a[j]) | (((u32)(u16)bq[j]) << 16);
    }
  }

  // ---- Q fragments straight from global -----------------------------------
  const int lq = l0 + wv * 16 + fr;
  short8 qf[2];
#pragma unroll
  for (int ks = 0; ks < 2; ++ks)
    qf[ks] = *(const short8*)(qkv + (size_t)lq * NQKVc + h * DHEADc + ks * 32 + hi * 8);

  __syncthreads();

  // ---- QK^T: S[jt] = Q(16x64) @ K(16x64)^T --------------------------------
  f32x4 S[NT] = {};
#pragma unroll
  for (int jt = 0; jt < NT; ++jt) {
#pragma unroll
    for (int ks = 0; ks < 2; ++ks) {
      int byte = (jt * 16 + fr) * 128 + ks * 64 + hi * 16;
      byte ^= (fr & 7) << 4;
      const short8 kf = *(const short8*)((const char*)Ks + byte);
      S[jt] = __builtin_amdgcn_mfma_f32_16x16x32_bf16(qf[ks], kf, S[jt], 0, 0, 0);
    }
  }

  // ---- bias + mask + softmax (rows = hi*4+r, cols = jt*16+fr) -------------
  float inv4[4];
#pragma unroll
  for (int r = 0; r < 4; ++r) {
    const int l = l0 + wv * 16 + hi * 4 + r;
    int st = l - 63;
    if (st < 0) st = 0;
    if (st > Lc - KSc) st = Lc - KSc;
    float mx = -3e38f;
#pragma unroll
    for (int jt = 0; jt < NT; ++jt) {
      const int pos = s_min + jt * 16 + fr;
      const int j = pos - st;
      float v = -3e38f;
      if (j >= 0 && j <= KSc - 1) v = S[jt][r] * 0.125f + rp[pos - l + KSc - 1];
      S[jt][r] = v;
      mx = fmaxf(mx, v);
    }
#pragma unroll
    for (int o = 1; o < 16; o <<= 1) mx = fmaxf(mx, __shfl_xor(mx, o));
    float sum = 0.f;
#pragma unroll
    for (int jt = 0; jt < NT; ++jt) {
      const float e = __expf(S[jt][r] - mx);
      S[jt][r] = e;
      sum += e;
    }
#pragma unroll
    for (int o = 1; o < 16; o <<= 1) sum += __shfl_xor(sum, o);
    inv4[r] = 1.f / sum;
  }

  // ---- write P (bf16, normalized) -----------------------------------------
#pragma unroll
  for (int jt = 0; jt < NT; ++jt)
#pragma unroll
    for (int r = 0; r < 4; ++r)
      Ps[wv][(hi * 4 + r) * PP + jt * 16 + fr] = f2b(S[jt][r] * inv4[r]);

  // ---- PV: O(16x64) = P(16x192) @ V(192x64) -------------------------------
  f32x4 O[4] = {};
#pragma unroll
  for (int ks = 0; ks < 6; ++ks) {
    const short8 pa =
        *(const short8*)((const char*)Ps[wv] + fr * (PP * 2) + ks * 64 + hi * 16);
#pragma unroll
    for (int dt = 0; dt < 4; ++dt) {
      int byte = (dt * 16 + fr) * (NR * 2) + ks * 64 + hi * 16;
      byte ^= (fr & 7) << 4;
      const short8 vb = *(const short8*)((const char*)Vt + byte);
      O[dt] = __builtin_amdgcn_mfma_f32_16x16x32_bf16(pa, vb, O[dt], 0, 0, 0);
    }
  }

  // ---- store O ------------------------------------------------------------
#pragma unroll
  for (int dt = 0; dt < 4; ++dt)
#pragma unroll
    for (int r = 0; r < 4; ++r)
      out[(size_t)(l0 + wv * 16 + hi * 4 + r) * DIMc + h * DHEADc + dt * 16 + fr] =
          f2b(O[dt][r]);
}

// ---------------------------------------------------------------------------
extern "C" void kernel_launch(void* const* d_in, const int* in_sizes, int n_in,
                              void* d_out, int out_size, void* d_ws,
                              size_t ws_size, hipStream_t stream) {
  const float* x      = (const float*)d_in[0];
  const float* ln1_g  = (const float*)d_in[1];
  const float* ln1_b  = (const float*)d_in[2];
  const float* qkv_w  = (const float*)d_in[3];
  const float* qkv_b  = (const float*)d_in[4];
  const float* rpb    = (const float*)d_in[5];
  const float* proj_w = (const float*)d_in[6];
  const float* proj_b = (const float*)d_in[7];
  const float* ln2_g  = (const float*)d_in[8];
  const float* ln2_b  = (const float*)d_in[9];
  const float* ff1_w  = (const float*)d_in[10];
  const float* ff1_b  = (const float*)d_in[11];
  const float* ff2_w  = (const float*)d_in[12];
  const float* ff2_b  = (const float*)d_in[13];
  float* out = (float*)d_out;

  char* ws = (char*)d_ws;
  u16*   lnbuf   = (u16*)(ws);                         // [0,2) MB
  u16*   qkvbuf  = (u16*)(ws + ((size_t)2  << 20));    // [2,8)
  u16*   attnbuf = (u16*)(ws + ((size_t)8  << 20));    // [8,10)
  float* x2      = (float*)(ws + ((size_t)10 << 20));  // [10,14)
  u16*   ff1buf  = (u16*)(ws + ((size_t)14 << 20));    // [14,22)
  u16*   wt_qkv  = (u16*)(ws + ((size_t)22 << 20));    // [22,23.5)
  u16*   wt_proj = (u16*)(ws + ((size_t)23 << 20) + ((size_t)512 << 10));
  u16*   wt_ff1  = (u16*)(ws + ((size_t)24 << 20));    // [24,26)
  u16*   wt_ff2  = (u16*)(ws + ((size_t)26 << 20));    // [26,28)
  u16*   parts   = (u16*)(ws + ((size_t)2  << 20));    // overlay [2,10) after proj

  wtrans_all<<<3072, 256, 0, stream>>>(qkv_w, proj_w, ff1_w, ff2_w,
                                       wt_qkv, wt_proj, wt_ff1, wt_ff2);

  // 1) LN1
  ln_kernel<<<Lc, 256, 0, stream>>>(x, ln1_g, ln1_b, lnbuf);
  // 2) QKV GEMM (bf16 out)
  mfma_gemm<0, 1, u16><<<dim3(NQKVc / 128, Lc / 128), 256, 0, stream>>>(
      lnbuf, wt_qkv, qkv_b, nullptr, qkvbuf, Lc, NQKVc, DIMc);
  // 3) attention (MFMA)
  attn_mfma<<<dim3(Lc / 64, HEADSc), 256, 0, stream>>>(qkvbuf, rpb, attnbuf);
  // 4) proj GEMM + residual(x) -> x2 (f32)
  mfma_gemm<2, 1, float><<<dim3(DIMc / 128, Lc / 128), 256, 0, stream>>>(
      attnbuf, wt_proj, proj_b, x, x2, Lc, DIMc, DIMc);
  // 5) LN2
  ln_kernel<<<Lc, 256, 0, stream>>>(x2, ln2_g, ln2_b, lnbuf);
  // 6) FF1 GEMM + GELU (bf16 out)
  mfma_gemm<1, 1, u16><<<dim3(4 * DIMc / 128, Lc / 128), 256, 0, stream>>>(
      lnbuf, wt_ff1, ff1_b, nullptr, ff1buf, Lc, 4 * DIMc, DIMc);
  // 7) FF2 GEMM split-K=4 -> bf16 partials (overlaid on dead qkv/attn bufs)
  mfma_gemm<3, 4, u16><<<dim3(DIMc / 128, Lc / 128, 4), 256, 0, stream>>>(
      ff1buf, wt_ff2, nullptr, nullptr, parts, Lc, DIMc, 4 * DIMc);
  // 8) reduce + bias + residual(x2) -> out (f32)
  ff2_reduce<<<(Lc * DIMc / 4) / 256, 256, 0, stream>>>(parts, x2, ff2_b, out);
}

// Round 5
// 89.786 us; speedup vs baseline: 5.2849x; 1.0652x over previous
//
#include <hip/hip_runtime.h>
#include <hip/hip_bf16.h>

static constexpr int Lc     = 2048;
static constexpr int DIMc   = 512;
static constexpr int HEADSc = 8;
static constexpr int DHEADc = 64;
static constexpr int KSc    = 127;
static constexpr int NQKVc  = 1536;

typedef __attribute__((ext_vector_type(8))) short short8;
typedef __attribute__((ext_vector_type(4))) float f32x4;
typedef unsigned short u16;
typedef unsigned int u32;

__device__ __forceinline__ float b2f(u16 s) {
  return __uint_as_float(((u32)s) << 16);
}
__device__ __forceinline__ u16 f2b(float x) {  // RNE
  u32 u = __float_as_uint(x);
  return (u16)((u + 0x7fffu + ((u >> 16) & 1u)) >> 16);
}
__device__ __forceinline__ void gload16(const void* g, void* l) {
  __builtin_amdgcn_global_load_lds(
      (const __attribute__((address_space(1))) u32*)g,
      (__attribute__((address_space(3))) u32*)l, 16, 0, 0);
}

// ---------------- fused weight transpose + f32->bf16: W[K][N] -> Wt[N][K] ---
__global__ __launch_bounds__(256) void wtrans_all(
    const float* __restrict__ w0, const float* __restrict__ w1,
    const float* __restrict__ w2, const float* __restrict__ w3,
    u16* __restrict__ o0, u16* __restrict__ o1, u16* __restrict__ o2,
    u16* __restrict__ o3) {
  int t = blockIdx.x;
  const float* W;
  u16* O;
  int K, N;
  if (t < 768)       { W = w0; O = o0; K = 512;  N = 1536; }
  else if (t < 1024) { W = w1; O = o1; K = 512;  N = 512;  t -= 768; }
  else if (t < 2048) { W = w2; O = o2; K = 512;  N = 2048; t -= 1024; }
  else               { W = w3; O = o3; K = 2048; N = 512;  t -= 2048; }
  const int nt = N >> 5;
  const int by = t / nt, bx = t % nt;
  __shared__ float tl[32][33];
  const int c = threadIdx.x & 31, r0 = threadIdx.x >> 5;
#pragma unroll
  for (int i = 0; i < 4; ++i) {
    const int r = r0 + i * 8;
    tl[r][c] = W[(size_t)(by * 32 + r) * N + bx * 32 + c];
  }
  __syncthreads();
#pragma unroll
  for (int i = 0; i < 4; ++i) {
    const int r = r0 + i * 8;
    O[(size_t)(bx * 32 + r) * K + by * 32 + c] = f2b(tl[c][r]);
  }
}

// ---------------- LayerNorm: f32 in -> bf16 out ----------------------------
__global__ __launch_bounds__(256) void ln_kernel(const float* __restrict__ in,
                                                 const float* __restrict__ g,
                                                 const float* __restrict__ b,
                                                 u16* __restrict__ out) {
  const int row = blockIdx.x;
  const int tid = threadIdx.x;
  const float* rp = in + (size_t)row * DIMc;
  float v0 = rp[tid];
  float v1 = rp[tid + 256];
  float s = v0 + v1;
  float sq = v0 * v0 + v1 * v1;
  __shared__ float rs[4], rq[4], stat[2];
#pragma unroll
  for (int o = 32; o > 0; o >>= 1) {
    s += __shfl_down(s, o);
    sq += __shfl_down(sq, o);
  }
  const int wid = tid >> 6, lane = tid & 63;
  if (lane == 0) { rs[wid] = s; rq[wid] = sq; }
  __syncthreads();
  if (tid == 0) {
    float S = rs[0] + rs[1] + rs[2] + rs[3];
    float Q = rq[0] + rq[1] + rq[2] + rq[3];
    float m = S / DIMc;
    float var = Q / DIMc - m * m;
    stat[0] = m;
    stat[1] = rsqrtf(var + 1e-5f);
  }
  __syncthreads();
  const float m = stat[0], r = stat[1];
  out[(size_t)row * DIMc + tid] = f2b((v0 - m) * r * g[tid] + b[tid]);
  out[(size_t)row * DIMc + tid + 256] =
      f2b((v1 - m) * r * g[tid + 256] + b[tid + 256]);
}

// -------- fused proj-split-K reduce + residual + LayerNorm2 ----------------
// v = x + proj_b + parts0 + parts1 ; x2 = v (f32) ; lnout = LN(v) (bf16)
__global__ __launch_bounds__(256) void ln2x_kernel(
    const u16* __restrict__ parts, const float* __restrict__ x,
    const float* __restrict__ pb, const float* __restrict__ g,
    const float* __restrict__ b, float* __restrict__ x2,
    u16* __restrict__ lnout) {
  const int row = blockIdx.x;
  const int tid = threadIdx.x;
  const size_t base = (size_t)row * DIMc;
  float v0, v1;
  {
    const int c0 = tid, c1 = tid + 256;
    v0 = x[base + c0] + pb[c0] + b2f(parts[base + c0]) +
         b2f(parts[(size_t)Lc * DIMc + base + c0]);
    v1 = x[base + c1] + pb[c1] + b2f(parts[base + c1]) +
         b2f(parts[(size_t)Lc * DIMc + base + c1]);
  }
  x2[base + tid] = v0;
  x2[base + tid + 256] = v1;
  float s = v0 + v1;
  float sq = v0 * v0 + v1 * v1;
  __shared__ float rs[4], rq[4], stat[2];
#pragma unroll
  for (int o = 32; o > 0; o >>= 1) {
    s += __shfl_down(s, o);
    sq += __shfl_down(sq, o);
  }
  const int wid = tid >> 6, lane = tid & 63;
  if (lane == 0) { rs[wid] = s; rq[wid] = sq; }
  __syncthreads();
  if (tid == 0) {
    float S = rs[0] + rs[1] + rs[2] + rs[3];
    float Q = rq[0] + rq[1] + rq[2] + rq[3];
    float m = S / DIMc;
    float var = Q / DIMc - m * m;
    stat[0] = m;
    stat[1] = rsqrtf(var + 1e-5f);
  }
  __syncthreads();
  const float m = stat[0], r = stat[1];
  lnout[base + tid] = f2b((v0 - m) * r * g[tid] + b[tid]);
  lnout[base + tid + 256] = f2b((v1 - m) * r * g[tid + 256] + b[tid + 256]);
}

// ---------------- MFMA GEMM (double-buffered T3-min pipeline) --------------
// C[M,N] = A[M,K](bf16) @ Bt[N,K](bf16)^T
// OP: 0 bias (bf16 out), 1 bias+GELU (bf16 out), 2 bias+res (f32 out),
//     3 split-K partial (bf16, no bias)
template <int OP, int SPLIT, typename OUT_T>
__global__ __launch_bounds__(256) void mfma_gemm(
    const u16* __restrict__ A, const u16* __restrict__ Bt,
    const float* __restrict__ bias, const float* __restrict__ res,
    OUT_T* __restrict__ C, int M, int N, int K) {
  constexpr int BM = 128, BN = 128, BK = 32;
  __shared__ __align__(16) u16 As[2][BM * BK];
  __shared__ __align__(16) u16 Bs[2][BM * BK];
  const int tid = threadIdx.x;
  const int wave = tid >> 6, lane = tid & 63;
  const int m0 = blockIdx.y * BM, n0 = blockIdx.x * BN;
  const int wm = (wave >> 1) * 64, wn = (wave & 1) * 64;
  const int z = (SPLIT > 1) ? blockIdx.z : 0;
  const int kslice = K / SPLIT;
  const int kbeg = z * kslice;
  const int T = kslice / BK;

  f32x4 acc[4][4] = {};

  const int fr = lane & 15;
  const int fk8 = (lane >> 4) * 8;

  // staging geometry (per wave: 1 KB of A, 1 KB of B per i)
  const int lin = tid * 16;  // byte offset within 4 KB half-tile
  const int srow = lin >> 6, scolb = lin & 63;
  const int ldsbase = (wave * 1024) >> 1;  // elem index

#define STAGE(k0, buf)                                                        \
  {                                                                           \
    _Pragma("unroll") for (int i = 0; i < 2; ++i) {                           \
      gload16(A + (size_t)(m0 + i * 64 + srow) * K + (k0) + (scolb >> 1),     \
              &As[buf][i * 2048 + ldsbase]);                                  \
      gload16(Bt + (size_t)(n0 + i * 64 + srow) * K + (k0) + (scolb >> 1),    \
              &Bs[buf][i * 2048 + ldsbase]);                                  \
    }                                                                         \
  }

  STAGE(kbeg, 0);
  __syncthreads();

  for (int t = 0; t < T; ++t) {
    const int cur = t & 1;
    if (t + 1 < T) STAGE(kbeg + (t + 1) * BK, cur ^ 1);

    short8 af[4], bfr[4];
#pragma unroll
    for (int i = 0; i < 4; ++i)
      af[i] = *(const short8*)&As[cur][(wm + i * 16 + fr) * BK + fk8];
#pragma unroll
    for (int j = 0; j < 4; ++j)
      bfr[j] = *(const short8*)&Bs[cur][(wn + j * 16 + fr) * BK + fk8];
#pragma unroll
    for (int i = 0; i < 4; ++i)
#pragma unroll
      for (int j = 0; j < 4; ++j)
        acc[i][j] = __builtin_amdgcn_mfma_f32_16x16x32_bf16(af[i], bfr[j],
                                                            acc[i][j], 0, 0, 0);
    __syncthreads();  // drains vmcnt: next tile's loads landed, buffers safe
  }
#undef STAGE

  const int cl = lane & 15;
  const int rbase = (lane >> 4) * 4;
#pragma unroll
  for (int i = 0; i < 4; ++i) {
#pragma unroll
    for (int j = 0; j < 4; ++j) {
      const int c = n0 + wn + j * 16 + cl;
      const float bv = (OP == 3) ? 0.f : bias[c];
#pragma unroll
      for (int r = 0; r < 4; ++r) {
        const int row = m0 + wm + i * 16 + rbase + r;
        float v = acc[i][j][r] + bv;
        if (OP == 1) v = 0.5f * v * (1.0f + erff(v * 0.70710678118f));
        const size_t o = (size_t)row * N + c;
        if (OP == 2) {
          ((float*)C)[o] = v + res[o];
        } else if (OP == 3) {
          ((u16*)C)[(size_t)z * M * N + o] = f2b(v);
        } else {
          ((u16*)C)[o] = f2b(v);
        }
      }
    }
  }
}

// ---------------- split-K reduce for ff2: out = x2 + bias + sum(parts) -----
__global__ __launch_bounds__(256) void ff2_reduce(const u16* __restrict__ part,
                                                  const float* __restrict__ x2,
                                                  const float* __restrict__ bias,
                                                  float* __restrict__ out) {
  const int i = blockIdx.x * 256 + threadIdx.x;  // vec4 id
  const size_t b = (size_t)i * 4;
  const int col = (int)(b & (DIMc - 1));
  const float4 r = *(const float4*)(x2 + b);
  const float4 bb = *(const float4*)(bias + col);
  float4 s = {r.x + bb.x, r.y + bb.y, r.z + bb.z, r.w + bb.w};
#pragma unroll
  for (int zz = 0; zz < 4; ++zz) {
    const ushort4 p =
        *(const ushort4*)(part + (size_t)zz * (Lc * DIMc) + b);
    s.x += b2f(p.x);
    s.y += b2f(p.y);
    s.z += b2f(p.z);
    s.w += b2f(p.w);
  }
  *(float4*)(out + b) = s;
}

// ---------------- MFMA neighborhood attention: 64 queries x 1 head / block -
__global__ __launch_bounds__(256) void attn_mfma(const u16* __restrict__ qkv,
                                                 const float* __restrict__ rpb,
                                                 u16* __restrict__ out) {
  constexpr int NR = 192, NT = 12, PP = 200;
  __shared__ __align__(16) u16 Ks[NR * DHEADc];   // [r][d], seg ^ (r&7)
  __shared__ __align__(16) u16 Vt[DHEADc * NR];   // [d][r], seg ^ (d&7)
  __shared__ __align__(16) u16 Ps[4][16 * PP];    // per-wave P, stride 200
  __shared__ float rp[2 * KSc - 1];
  const int h = blockIdx.y, l0 = blockIdx.x * 64, tid = threadIdx.x;
  const int wv = tid >> 6, lane = tid & 63;
  const int fr = lane & 15, hi = lane >> 4;

  int s_min = l0 - 63;
  if (s_min < 0) s_min = 0;
  if (s_min > Lc - KSc) s_min = Lc - KSc;

  for (int i = tid; i < 2 * KSc - 1; i += 256) rp[i] = rpb[h * (2 * KSc - 1) + i];

  // ---- K stage: global_load_lds, pre-swizzled source, linear LDS ----------
#pragma unroll
  for (int rd = 0; rd < 6; ++rd) {
    const int linear = rd * 4096 + wv * 1024 + lane * 16;  // byte
    const int row = linear >> 7;          // 128B per row
    const int seg = (linear >> 4) & 7;
    const int segp = seg ^ (row & 7);
    int gl = s_min + row;
    if (gl > Lc - 1) gl = Lc - 1;
    gload16(qkv + (size_t)gl * NQKVc + DIMc + h * DHEADc + segp * 8,
            (char*)Ks + rd * 4096 + wv * 1024);
  }

  // ---- V stage: reg transpose -> Vt[d][r], swizzled b32 writes ------------
#pragma unroll
  for (int rd = 0; rd < 3; ++rd) {
    const int t = rd * 256 + tid;
    const int rpair = t >> 3, seg = t & 7;
    const int r0 = rpair * 2;
    int g0 = s_min + r0, g1 = s_min + r0 + 1;
    if (g0 > Lc - 1) g0 = Lc - 1;
    if (g1 > Lc - 1) g1 = Lc - 1;
    const short8 a =
        *(const short8*)(qkv + (size_t)g0 * NQKVc + 2 * DIMc + h * DHEADc + seg * 8);
    const short8 bq =
        *(const short8*)(qkv + (size_t)g1 * NQKVc + 2 * DIMc + h * DHEADc + seg * 8);
#pragma unroll
    for (int j = 0; j < 8; ++j) {
      const int d = seg * 8 + j;
      int byte = d * (NR * 2) + r0 * 2;
      byte ^= (d & 7) << 4;
      *(u32*)((char*)Vt + byte) =
          ((u32)(u16)a[j]) | (((u32)(u16)bq[j]) << 16);
    }
  }

  // ---- Q fragments straight from global -----------------------------------
  const int lq = l0 + wv * 16 + fr;
  short8 qf[2];
#pragma unroll
  for (int ks = 0; ks < 2; ++ks)
    qf[ks] = *(const short8*)(qkv + (size_t)lq * NQKVc + h * DHEADc + ks * 32 + hi * 8);

  __syncthreads();

  // ---- QK^T: S[jt] = Q(16x64) @ K(16x64)^T --------------------------------
  f32x4 S[NT] = {};
#pragma unroll
  for (int jt = 0; jt < NT; ++jt) {
#pragma unroll
    for (int ks = 0; ks < 2; ++ks) {
      int byte = (jt * 16 + fr) * 128 + ks * 64 + hi * 16;
      byte ^= (fr & 7) << 4;
      const short8 kf = *(const short8*)((const char*)Ks + byte);
      S[jt] = __builtin_amdgcn_mfma_f32_16x16x32_bf16(qf[ks], kf, S[jt], 0, 0, 0);
    }
  }

  // ---- bias + mask + softmax (rows = hi*4+r, cols = jt*16+fr) -------------
  float inv4[4];
#pragma unroll
  for (int r = 0; r < 4; ++r) {
    const int l = l0 + wv * 16 + hi * 4 + r;
    int st = l - 63;
    if (st < 0) st = 0;
    if (st > Lc - KSc) st = Lc - KSc;
    float mx = -3e38f;
#pragma unroll
    for (int jt = 0; jt < NT; ++jt) {
      const int pos = s_min + jt * 16 + fr;
      const int j = pos - st;
      float v = -3e38f;
      if (j >= 0 && j <= KSc - 1) v = S[jt][r] * 0.125f + rp[pos - l + KSc - 1];
      S[jt][r] = v;
      mx = fmaxf(mx, v);
    }
#pragma unroll
    for (int o = 1; o < 16; o <<= 1) mx = fmaxf(mx, __shfl_xor(mx, o));
    float sum = 0.f;
#pragma unroll
    for (int jt = 0; jt < NT; ++jt) {
      const float e = __expf(S[jt][r] - mx);
      S[jt][r] = e;
      sum += e;
    }
#pragma unroll
    for (int o = 1; o < 16; o <<= 1) sum += __shfl_xor(sum, o);
    inv4[r] = 1.f / sum;
  }

  // ---- write P (bf16, normalized) -----------------------------------------
#pragma unroll
  for (int jt = 0; jt < NT; ++jt)
#pragma unroll
    for (int r = 0; r < 4; ++r)
      Ps[wv][(hi * 4 + r) * PP + jt * 16 + fr] = f2b(S[jt][r] * inv4[r]);

  // ---- PV: O(16x64) = P(16x192) @ V(192x64) -------------------------------
  f32x4 O[4] = {};
#pragma unroll
  for (int ks = 0; ks < 6; ++ks) {
    const short8 pa =
        *(const short8*)((const char*)Ps[wv] + fr * (PP * 2) + ks * 64 + hi * 16);
#pragma unroll
    for (int dt = 0; dt < 4; ++dt) {
      int byte = (dt * 16 + fr) * (NR * 2) + ks * 64 + hi * 16;
      byte ^= (fr & 7) << 4;
      const short8 vb = *(const short8*)((const char*)Vt + byte);
      O[dt] = __builtin_amdgcn_mfma_f32_16x16x32_bf16(pa, vb, O[dt], 0, 0, 0);
    }
  }

  // ---- store O ------------------------------------------------------------
#pragma unroll
  for (int dt = 0; dt < 4; ++dt)
#pragma unroll
    for (int r = 0; r < 4; ++r)
      out[(size_t)(l0 + wv * 16 + hi * 4 + r) * DIMc + h * DHEADc + dt * 16 + fr] =
          f2b(O[dt][r]);
}

// ---------------------------------------------------------------------------
extern "C" void kernel_launch(void* const* d_in, const int* in_sizes, int n_in,
                              void* d_out, int out_size, void* d_ws,
                              size_t ws_size, hipStream_t stream) {
  const float* x      = (const float*)d_in[0];
  const float* ln1_g  = (const float*)d_in[1];
  const float* ln1_b  = (const float*)d_in[2];
  const float* qkv_w  = (const float*)d_in[3];
  const float* qkv_b  = (const float*)d_in[4];
  const float* rpb    = (const float*)d_in[5];
  const float* proj_w = (const float*)d_in[6];
  const float* proj_b = (const float*)d_in[7];
  const float* ln2_g  = (const float*)d_in[8];
  const float* ln2_b  = (const float*)d_in[9];
  const float* ff1_w  = (const float*)d_in[10];
  const float* ff1_b  = (const float*)d_in[11];
  const float* ff2_w  = (const float*)d_in[12];
  const float* ff2_b  = (const float*)d_in[13];
  float* out = (float*)d_out;

  char* ws = (char*)d_ws;
  u16*   lnbuf   = (u16*)(ws);                         // [0,2) MB
  u16*   qkvbuf  = (u16*)(ws + ((size_t)2  << 20));    // [2,8)
  u16*   attnbuf = (u16*)(ws + ((size_t)8  << 20));    // [8,10)
  float* x2      = (float*)(ws + ((size_t)10 << 20));  // [10,14)
  u16*   ff1buf  = (u16*)(ws + ((size_t)14 << 20));    // [14,22)
  u16*   wt_qkv  = (u16*)(ws + ((size_t)22 << 20));    // [22,23.5)
  u16*   wt_proj = (u16*)(ws + ((size_t)23 << 20) + ((size_t)512 << 10));
  u16*   wt_ff1  = (u16*)(ws + ((size_t)24 << 20));    // [24,26)
  u16*   wt_ff2  = (u16*)(ws + ((size_t)26 << 20));    // [26,28)
  u16*   parts   = (u16*)(ws + ((size_t)2  << 20));    // overlay [2,10)

  wtrans_all<<<3072, 256, 0, stream>>>(qkv_w, proj_w, ff1_w, ff2_w,
                                       wt_qkv, wt_proj, wt_ff1, wt_ff2);

  // 1) LN1
  ln_kernel<<<Lc, 256, 0, stream>>>(x, ln1_g, ln1_b, lnbuf);
  // 2) QKV GEMM (bf16 out)
  mfma_gemm<0, 1, u16><<<dim3(NQKVc / 128, Lc / 128), 256, 0, stream>>>(
      lnbuf, wt_qkv, qkv_b, nullptr, qkvbuf, Lc, NQKVc, DIMc);
  // 3) attention (MFMA)
  attn_mfma<<<dim3(Lc / 64, HEADSc), 256, 0, stream>>>(qkvbuf, rpb, attnbuf);
  // 4) proj GEMM split-K=2 -> bf16 partials (overlaid on dead qkv buf [2,6))
  mfma_gemm<3, 2, u16><<<dim3(DIMc / 128, Lc / 128, 2), 256, 0, stream>>>(
      attnbuf, wt_proj, nullptr, nullptr, parts, Lc, DIMc, DIMc);
  // 5) fused proj-reduce + residual(x) + LN2: writes x2 (f32) + lnbuf (bf16)
  ln2x_kernel<<<Lc, 256, 0, stream>>>(parts, x, proj_b, ln2_g, ln2_b, x2, lnbuf);
  // 6) FF1 GEMM + GELU (bf16 out)
  mfma_gemm<1, 1, u16><<<dim3(4 * DIMc / 128, Lc / 128), 256, 0, stream>>>(
      lnbuf, wt_ff1, ff1_b, nullptr, ff1buf, Lc, 4 * DIMc, DIMc);
  // 7) FF2 GEMM split-K=4 -> bf16 partials (overlay [2,10))
  mfma_gemm<3, 4, u16><<<dim3(DIMc / 128, Lc / 128, 4), 256, 0, stream>>>(
      ff1buf, wt_ff2, nullptr, nullptr, parts, Lc, DIMc, 4 * DIMc);
  // 8) reduce + bias + residual(x2) -> out (f32)
  ff2_reduce<<<(Lc * DIMc / 4) / 256, 256, 0, stream>>>(parts, x2, ff2_b, out);
}

// Round 6
// 79.385 us; speedup vs baseline: 5.9774x; 1.1310x over previous
//
#include <hip/hip_runtime.h>
#include <hip/hip_bf16.h>

static constexpr int Lc     = 2048;
static constexpr int DIMc   = 512;
static constexpr int HEADSc = 8;
static constexpr int DHEADc = 64;
static constexpr int KSc    = 127;
static constexpr int NQKVc  = 1536;

typedef __attribute__((ext_vector_type(8))) short short8;
typedef __attribute__((ext_vector_type(4))) float f32x4;
typedef unsigned short u16;
typedef unsigned int u32;

__device__ __forceinline__ float b2f(u16 s) {
  return __uint_as_float(((u32)s) << 16);
}
__device__ __forceinline__ u16 f2b(float x) {  // RNE
  u32 u = __float_as_uint(x);
  return (u16)((u + 0x7fffu + ((u >> 16) & 1u)) >> 16);
}
__device__ __forceinline__ void gload16(const void* g, void* l) {
  __builtin_amdgcn_global_load_lds(
      (const __attribute__((address_space(1))) u32*)g,
      (__attribute__((address_space(3))) u32*)l, 16, 0, 0);
}

// ------- fused: weight transposes (blocks 0..3071) + LN1 (blocks 3072..5119)
__global__ __launch_bounds__(256) void prep_kernel(
    const float* __restrict__ w0, const float* __restrict__ w1,
    const float* __restrict__ w2, const float* __restrict__ w3,
    u16* __restrict__ o0, u16* __restrict__ o1, u16* __restrict__ o2,
    u16* __restrict__ o3, const float* __restrict__ xin,
    const float* __restrict__ g, const float* __restrict__ b,
    u16* __restrict__ lnout) {
  __shared__ float tl[32][33];
  __shared__ float rs[4], rq[4], stat[2];
  const int tid = threadIdx.x;
  if (blockIdx.x >= 3072) {  // ---------------- LN1 path
    const int row = blockIdx.x - 3072;
    const float* rp = xin + (size_t)row * DIMc;
    float v0 = rp[tid];
    float v1 = rp[tid + 256];
    float s = v0 + v1;
    float sq = v0 * v0 + v1 * v1;
#pragma unroll
    for (int o = 32; o > 0; o >>= 1) {
      s += __shfl_down(s, o);
      sq += __shfl_down(sq, o);
    }
    const int wid = tid >> 6, lane = tid & 63;
    if (lane == 0) { rs[wid] = s; rq[wid] = sq; }
    __syncthreads();
    if (tid == 0) {
      float S = rs[0] + rs[1] + rs[2] + rs[3];
      float Q = rq[0] + rq[1] + rq[2] + rq[3];
      float m = S / DIMc;
      float var = Q / DIMc - m * m;
      stat[0] = m;
      stat[1] = rsqrtf(var + 1e-5f);
    }
    __syncthreads();
    const float m = stat[0], r = stat[1];
    lnout[(size_t)row * DIMc + tid] = f2b((v0 - m) * r * g[tid] + b[tid]);
    lnout[(size_t)row * DIMc + tid + 256] =
        f2b((v1 - m) * r * g[tid + 256] + b[tid + 256]);
    return;
  }
  // ---------------- wtrans path: W[K][N] -> Wt[N][K] (bf16)
  int t = blockIdx.x;
  const float* W;
  u16* O;
  int K, N;
  if (t < 768)       { W = w0; O = o0; K = 512;  N = 1536; }
  else if (t < 1024) { W = w1; O = o1; K = 512;  N = 512;  t -= 768; }
  else if (t < 2048) { W = w2; O = o2; K = 512;  N = 2048; t -= 1024; }
  else               { W = w3; O = o3; K = 2048; N = 512;  t -= 2048; }
  const int nt = N >> 5;
  const int by = t / nt, bx = t % nt;
  const int c = tid & 31, r0 = tid >> 5;
#pragma unroll
  for (int i = 0; i < 4; ++i) {
    const int r = r0 + i * 8;
    tl[r][c] = W[(size_t)(by * 32 + r) * N + bx * 32 + c];
  }
  __syncthreads();
#pragma unroll
  for (int i = 0; i < 4; ++i) {
    const int r = r0 + i * 8;
    O[(size_t)(bx * 32 + r) * K + by * 32 + c] = f2b(tl[c][r]);
  }
}

// -------- fused proj-split-K reduce + residual + LayerNorm2 ----------------
__global__ __launch_bounds__(256) void ln2x_kernel(
    const u16* __restrict__ parts, const float* __restrict__ x,
    const float* __restrict__ pb, const float* __restrict__ g,
    const float* __restrict__ b, float* __restrict__ x2,
    u16* __restrict__ lnout) {
  const int row = blockIdx.x;
  const int tid = threadIdx.x;
  const size_t base = (size_t)row * DIMc;
  float v0, v1;
  {
    const int c0 = tid, c1 = tid + 256;
    v0 = x[base + c0] + pb[c0] + b2f(parts[base + c0]) +
         b2f(parts[(size_t)Lc * DIMc + base + c0]);
    v1 = x[base + c1] + pb[c1] + b2f(parts[base + c1]) +
         b2f(parts[(size_t)Lc * DIMc + base + c1]);
  }
  x2[base + tid] = v0;
  x2[base + tid + 256] = v1;
  float s = v0 + v1;
  float sq = v0 * v0 + v1 * v1;
  __shared__ float rs[4], rq[4], stat[2];
#pragma unroll
  for (int o = 32; o > 0; o >>= 1) {
    s += __shfl_down(s, o);
    sq += __shfl_down(sq, o);
  }
  const int wid = tid >> 6, lane = tid & 63;
  if (lane == 0) { rs[wid] = s; rq[wid] = sq; }
  __syncthreads();
  if (tid == 0) {
    float S = rs[0] + rs[1] + rs[2] + rs[3];
    float Q = rq[0] + rq[1] + rq[2] + rq[3];
    float m = S / DIMc;
    float var = Q / DIMc - m * m;
    stat[0] = m;
    stat[1] = rsqrtf(var + 1e-5f);
  }
  __syncthreads();
  const float m = stat[0], r = stat[1];
  lnout[base + tid] = f2b((v0 - m) * r * g[tid] + b[tid]);
  lnout[base + tid + 256] = f2b((v1 - m) * r * g[tid + 256] + b[tid + 256]);
}

// ---------------- MFMA GEMM: 64x64 tile, 2 waves, double-buffered ----------
// C[M,N] = A[M,K](bf16) @ Bt[N,K](bf16)^T
// OP: 0 bias (bf16 out), 1 bias+GELU (bf16 out), 3 split-K partial (bf16)
template <int OP, int SPLIT, typename OUT_T>
__global__ __launch_bounds__(128) void mfma_gemm(
    const u16* __restrict__ A, const u16* __restrict__ Bt,
    const float* __restrict__ bias, OUT_T* __restrict__ C, int M, int N,
    int K) {
  constexpr int BK = 32;
  __shared__ __align__(16) u16 As[2][64 * BK];
  __shared__ __align__(16) u16 Bs[2][64 * BK];
  const int tid = threadIdx.x;
  const int wave = tid >> 6, lane = tid & 63;
  const int m0 = blockIdx.y * 64, n0 = blockIdx.x * 64;
  const int wn = wave * 32;
  const int z = (SPLIT > 1) ? blockIdx.z : 0;
  const int kslice = K / SPLIT;
  const int kbeg = z * kslice;
  const int T = kslice / BK;

  f32x4 acc[4][2] = {};

  const int fr = lane & 15;
  const int fk8 = (lane >> 4) * 8;

  // staging: 128 threads x 16B = 2KB per i-step; tile = 4KB (64 rows x 64B)
  const int srow = tid >> 2;            // 0..31
  const int scol = (tid & 3) * 8;       // elem offset
  const int ldsbase = wave * 512;       // elem: wave-uniform base + lane*8

#define STAGE(k0, buf)                                                        \
  {                                                                           \
    _Pragma("unroll") for (int i = 0; i < 2; ++i) {                           \
      gload16(A + (size_t)(m0 + i * 32 + srow) * K + (k0) + scol,             \
              &As[buf][i * 1024 + ldsbase]);                                  \
      gload16(Bt + (size_t)(n0 + i * 32 + srow) * K + (k0) + scol,            \
              &Bs[buf][i * 1024 + ldsbase]);                                  \
    }                                                                         \
  }

  STAGE(kbeg, 0);
  __syncthreads();

  for (int t = 0; t < T; ++t) {
    const int cur = t & 1;
    if (t + 1 < T) STAGE(kbeg + (t + 1) * BK, cur ^ 1);

    short8 af[4], bf[2];
#pragma unroll
    for (int i = 0; i < 4; ++i)
      af[i] = *(const short8*)&As[cur][(i * 16 + fr) * BK + fk8];
#pragma unroll
    for (int j = 0; j < 2; ++j)
      bf[j] = *(const short8*)&Bs[cur][(wn + j * 16 + fr) * BK + fk8];
#pragma unroll
    for (int i = 0; i < 4; ++i)
#pragma unroll
      for (int j = 0; j < 2; ++j)
        acc[i][j] = __builtin_amdgcn_mfma_f32_16x16x32_bf16(af[i], bf[j],
                                                            acc[i][j], 0, 0, 0);
    __syncthreads();
  }
#undef STAGE

  const int cl = lane & 15;
  const int rbase = (lane >> 4) * 4;
#pragma unroll
  for (int i = 0; i < 4; ++i) {
#pragma unroll
    for (int j = 0; j < 2; ++j) {
      const int c = n0 + wn + j * 16 + cl;
      const float bv = (OP == 3) ? 0.f : bias[c];
#pragma unroll
      for (int r = 0; r < 4; ++r) {
        const int row = m0 + i * 16 + rbase + r;
        float v = acc[i][j][r] + bv;
        if (OP == 1) v = 0.5f * v * (1.0f + erff(v * 0.70710678118f));
        const size_t o = (size_t)row * N + c;
        if (OP == 3) {
          ((u16*)C)[(size_t)z * M * N + o] = f2b(v);
        } else {
          ((u16*)C)[o] = f2b(v);
        }
      }
    }
  }
}

// ---------------- split-K reduce for ff2: out = x2 + bias + sum(parts) -----
__global__ __launch_bounds__(256) void ff2_reduce(const u16* __restrict__ part,
                                                  const float* __restrict__ x2,
                                                  const float* __restrict__ bias,
                                                  float* __restrict__ out) {
  const int i = blockIdx.x * 256 + threadIdx.x;  // vec4 id
  const size_t b = (size_t)i * 4;
  const int col = (int)(b & (DIMc - 1));
  const float4 r = *(const float4*)(x2 + b);
  const float4 bb = *(const float4*)(bias + col);
  float4 s = {r.x + bb.x, r.y + bb.y, r.z + bb.z, r.w + bb.w};
#pragma unroll
  for (int zz = 0; zz < 4; ++zz) {
    const ushort4 p =
        *(const ushort4*)(part + (size_t)zz * (Lc * DIMc) + b);
    s.x += b2f(p.x);
    s.y += b2f(p.y);
    s.z += b2f(p.z);
    s.w += b2f(p.w);
  }
  *(float4*)(out + b) = s;
}

// ---------------- MFMA neighborhood attention: 64 queries x 1 head / block -
__global__ __launch_bounds__(256) void attn_mfma(const u16* __restrict__ qkv,
                                                 const float* __restrict__ rpb,
                                                 u16* __restrict__ out) {
  constexpr int NR = 192, NT = 12, PP = 200;
  __shared__ __align__(16) u16 Ks[NR * DHEADc];   // [r][d], seg ^ (r&7)
  __shared__ __align__(16) u16 Vt[DHEADc * NR];   // [d][r], seg ^ (d&7)
  __shared__ __align__(16) u16 Ps[4][16 * PP];    // per-wave P, stride 200
  __shared__ float rp[2 * KSc - 1];
  const int h = blockIdx.y, l0 = blockIdx.x * 64, tid = threadIdx.x;
  const int wv = tid >> 6, lane = tid & 63;
  const int fr = lane & 15, hi = lane >> 4;

  int s_min = l0 - 63;
  if (s_min < 0) s_min = 0;
  if (s_min > Lc - KSc) s_min = Lc - KSc;

  for (int i = tid; i < 2 * KSc - 1; i += 256) rp[i] = rpb[h * (2 * KSc - 1) + i];

  // ---- K stage: global_load_lds, pre-swizzled source, linear LDS ----------
#pragma unroll
  for (int rd = 0; rd < 6; ++rd) {
    const int linear = rd * 4096 + wv * 1024 + lane * 16;  // byte
    const int row = linear >> 7;          // 128B per row
    const int seg = (linear >> 4) & 7;
    const int segp = seg ^ (row & 7);
    int gl = s_min + row;
    if (gl > Lc - 1) gl = Lc - 1;
    gload16(qkv + (size_t)gl * NQKVc + DIMc + h * DHEADc + segp * 8,
            (char*)Ks + rd * 4096 + wv * 1024);
  }

  // ---- V stage: reg transpose -> Vt[d][r], swizzled b32 writes ------------
#pragma unroll
  for (int rd = 0; rd < 3; ++rd) {
    const int t = rd * 256 + tid;
    const int rpair = t >> 3, seg = t & 7;
    const int r0 = rpair * 2;
    int g0 = s_min + r0, g1 = s_min + r0 + 1;
    if (g0 > Lc - 1) g0 = Lc - 1;
    if (g1 > Lc - 1) g1 = Lc - 1;
    const short8 a =
        *(const short8*)(qkv + (size_t)g0 * NQKVc + 2 * DIMc + h * DHEADc + seg * 8);
    const short8 bq =
        *(const short8*)(qkv + (size_t)g1 * NQKVc + 2 * DIMc + h * DHEADc + seg * 8);
#pragma unroll
    for (int j = 0; j < 8; ++j) {
      const int d = seg * 8 + j;
      int byte = d * (NR * 2) + r0 * 2;
      byte ^= (d & 7) << 4;
      *(u32*)((char*)Vt + byte) =
          ((u32)(u16)a[j]) | (((u32)(u16)bq[j]) << 16);
    }
  }

  // ---- Q fragments straight from global -----------------------------------
  const int lq = l0 + wv * 16 + fr;
  short8 qf[2];
#pragma unroll
  for (int ks = 0; ks < 2; ++ks)
    qf[ks] = *(const short8*)(qkv + (size_t)lq * NQKVc + h * DHEADc + ks * 32 + hi * 8);

  __syncthreads();

  // ---- QK^T: S[jt] = Q(16x64) @ K(16x64)^T --------------------------------
  f32x4 S[NT] = {};
#pragma unroll
  for (int jt = 0; jt < NT; ++jt) {
#pragma unroll
    for (int ks = 0; ks < 2; ++ks) {
      int byte = (jt * 16 + fr) * 128 + ks * 64 + hi * 16;
      byte ^= (fr & 7) << 4;
      const short8 kf = *(const short8*)((const char*)Ks + byte);
      S[jt] = __builtin_amdgcn_mfma_f32_16x16x32_bf16(qf[ks], kf, S[jt], 0, 0, 0);
    }
  }

  // ---- bias + mask + softmax (rows = hi*4+r, cols = jt*16+fr) -------------
  float inv4[4];
#pragma unroll
  for (int r = 0; r < 4; ++r) {
    const int l = l0 + wv * 16 + hi * 4 + r;
    int st = l - 63;
    if (st < 0) st = 0;
    if (st > Lc - KSc) st = Lc - KSc;
    float mx = -3e38f;
#pragma unroll
    for (int jt = 0; jt < NT; ++jt) {
      const int pos = s_min + jt * 16 + fr;
      const int j = pos - st;
      float v = -3e38f;
      if (j >= 0 && j <= KSc - 1) v = S[jt][r] * 0.125f + rp[pos - l + KSc - 1];
      S[jt][r] = v;
      mx = fmaxf(mx, v);
    }
#pragma unroll
    for (int o = 1; o < 16; o <<= 1) mx = fmaxf(mx, __shfl_xor(mx, o));
    float sum = 0.f;
#pragma unroll
    for (int jt = 0; jt < NT; ++jt) {
      const float e = __expf(S[jt][r] - mx);
      S[jt][r] = e;
      sum += e;
    }
#pragma unroll
    for (int o = 1; o < 16; o <<= 1) sum += __shfl_xor(sum, o);
    inv4[r] = 1.f / sum;
  }

  // ---- write P (bf16, normalized) -----------------------------------------
#pragma unroll
  for (int jt = 0; jt < NT; ++jt)
#pragma unroll
    for (int r = 0; r < 4; ++r)
      Ps[wv][(hi * 4 + r) * PP + jt * 16 + fr] = f2b(S[jt][r] * inv4[r]);

  // ---- PV: O(16x64) = P(16x192) @ V(192x64) -------------------------------
  f32x4 O[4] = {};
#pragma unroll
  for (int ks = 0; ks < 6; ++ks) {
    const short8 pa =
        *(const short8*)((const char*)Ps[wv] + fr * (PP * 2) + ks * 64 + hi * 16);
#pragma unroll
    for (int dt = 0; dt < 4; ++dt) {
      int byte = (dt * 16 + fr) * (NR * 2) + ks * 64 + hi * 16;
      byte ^= (fr & 7) << 4;
      const short8 vb = *(const short8*)((const char*)Vt + byte);
      O[dt] = __builtin_amdgcn_mfma_f32_16x16x32_bf16(pa, vb, O[dt], 0, 0, 0);
    }
  }

  // ---- store O ------------------------------------------------------------
#pragma unroll
  for (int dt = 0; dt < 4; ++dt)
#pragma unroll
    for (int r = 0; r < 4; ++r)
      out[(size_t)(l0 + wv * 16 + hi * 4 + r) * DIMc + h * DHEADc + dt * 16 + fr] =
          f2b(O[dt][r]);
}

// ---------------------------------------------------------------------------
extern "C" void kernel_launch(void* const* d_in, const int* in_sizes, int n_in,
                              void* d_out, int out_size, void* d_ws,
                              size_t ws_size, hipStream_t stream) {
  const float* x      = (const float*)d_in[0];
  const float* ln1_g  = (const float*)d_in[1];
  const float* ln1_b  = (const float*)d_in[2];
  const float* qkv_w  = (const float*)d_in[3];
  const float* qkv_b  = (const float*)d_in[4];
  const float* rpb    = (const float*)d_in[5];
  const float* proj_w = (const float*)d_in[6];
  const float* proj_b = (const float*)d_in[7];
  const float* ln2_g  = (const float*)d_in[8];
  const float* ln2_b  = (const float*)d_in[9];
  const float* ff1_w  = (const float*)d_in[10];
  const float* ff1_b  = (const float*)d_in[11];
  const float* ff2_w  = (const float*)d_in[12];
  const float* ff2_b  = (const float*)d_in[13];
  float* out = (float*)d_out;

  char* ws = (char*)d_ws;
  u16*   lnbuf   = (u16*)(ws);                         // [0,2) MB
  u16*   qkvbuf  = (u16*)(ws + ((size_t)2  << 20));    // [2,8)
  u16*   attnbuf = (u16*)(ws + ((size_t)8  << 20));    // [8,10)
  float* x2      = (float*)(ws + ((size_t)10 << 20));  // [10,14)
  u16*   ff1buf  = (u16*)(ws + ((size_t)14 << 20));    // [14,22)
  u16*   wt_qkv  = (u16*)(ws + ((size_t)22 << 20));    // [22,23.5)
  u16*   wt_proj = (u16*)(ws + ((size_t)23 << 20) + ((size_t)512 << 10));
  u16*   wt_ff1  = (u16*)(ws + ((size_t)24 << 20));    // [24,26)
  u16*   wt_ff2  = (u16*)(ws + ((size_t)26 << 20));    // [26,28)
  u16*   parts   = (u16*)(ws + ((size_t)2  << 20));    // overlay [2,10)

  // 1) weight transposes + LN1 (fused, disjoint block ranges)
  prep_kernel<<<5120, 256, 0, stream>>>(qkv_w, proj_w, ff1_w, ff2_w, wt_qkv,
                                        wt_proj, wt_ff1, wt_ff2, x, ln1_g,
                                        ln1_b, lnbuf);
  // 2) QKV GEMM (bf16 out)
  mfma_gemm<0, 1, u16><<<dim3(NQKVc / 64, Lc / 64), 128, 0, stream>>>(
      lnbuf, wt_qkv, qkv_b, qkvbuf, Lc, NQKVc, DIMc);
  // 3) attention (MFMA)
  attn_mfma<<<dim3(Lc / 64, HEADSc), 256, 0, stream>>>(qkvbuf, rpb, attnbuf);
  // 4) proj GEMM split-K=2 -> bf16 partials
  mfma_gemm<3, 2, u16><<<dim3(DIMc / 64, Lc / 64, 2), 128, 0, stream>>>(
      attnbuf, wt_proj, nullptr, parts, Lc, DIMc, DIMc);
  // 5) fused proj-reduce + residual(x) + LN2: writes x2 (f32) + lnbuf (bf16)
  ln2x_kernel<<<Lc, 256, 0, stream>>>(parts, x, proj_b, ln2_g, ln2_b, x2, lnbuf);
  // 6) FF1 GEMM + GELU (bf16 out)
  mfma_gemm<1, 1, u16><<<dim3(4 * DIMc / 64, Lc / 64), 128, 0, stream>>>(
      lnbuf, wt_ff1, ff1_b, ff1buf, Lc, 4 * DIMc, DIMc);
  // 7) FF2 GEMM split-K=4 -> bf16 partials (overlay [2,10))
  mfma_gemm<3, 4, u16><<<dim3(DIMc / 64, Lc / 64, 4), 128, 0, stream>>>(
      ff1buf, wt_ff2, nullptr, parts, Lc, DIMc, 4 * DIMc);
  // 8) reduce + bias + residual(x2) -> out (f32)
  ff2_reduce<<<(Lc * DIMc / 4) / 256, 256, 0, stream>>>(parts, x2, ff2_b, out);
}